// Round 11
// baseline (2217.782 us; speedup 1.0000x reference)
//
#include <hip/hip_runtime.h>

#define BATCH 4096

typedef __attribute__((ext_vector_type(8))) short bf16x8;
typedef __attribute__((ext_vector_type(4))) float f32x4;

// Manual RNE float->bf16 (round half to even), matches HW/NumPy for normal finite values.
__device__ __forceinline__ unsigned short f2bf(float f) {
    union { float f; unsigned u; } v; v.f = f;
    unsigned r = v.u + 0x7fffu + ((v.u >> 16) & 1u);
    return (unsigned short)(r >> 16);
}
__device__ __forceinline__ unsigned packbf(float a, float b) {
    return (unsigned)f2bf(a) | ((unsigned)f2bf(b) << 16);
}

// 16 features for one x: o[0..3] = cos(1x..8x) pairs, o[4..7] = sin(1x..8x) pairs (bf16x2).
__device__ __forceinline__ void feats16(float x, unsigned o[8]) {
    float c1 = __cosf(x), s1 = __sinf(x);
    float cs[8], sn[8];
    cs[0] = c1; sn[0] = s1;
    #pragma unroll
    for (int k = 1; k < 8; ++k) {
        cs[k] = c1 * cs[k-1] - s1 * sn[k-1];
        sn[k] = s1 * cs[k-1] + c1 * sn[k-1];
    }
    #pragma unroll
    for (int k = 0; k < 4; ++k) {
        o[k]     = packbf(cs[2*k], cs[2*k+1]);
        o[4 + k] = packbf(sn[2*k], sn[2*k+1]);
    }
}

// Async global->LDS, 16 B per lane. LDS dest is wave-uniform base; HW adds lane*16.
__device__ __forceinline__ void gload_lds16(const void* g, void* l) {
    __builtin_amdgcn_global_load_lds(
        (__attribute__((address_space(1))) void*)(g),
        (__attribute__((address_space(3))) void*)(l), 16, 0, 0);
}

// ---------------- one-shot precompute kernels ----------------

// C [2][OUT][IN][8] f32  ->  B [OUT][IN*16] bf16, k = i*16 + d*8 + g
template <int IN, int OUT>
__global__ void conv_C(const float* __restrict__ C, unsigned short* __restrict__ B) {
    const int i = blockIdx.x * 256 + threadIdx.x;
    const int j = blockIdx.y;
    const float* c0 = C + ((size_t)j * IN + i) * 8;            // d=0 (cos) plane
    const float* c1 = c0 + (size_t)OUT * IN * 8;               // d=1 (sin) plane
    const float4 a0 = *(const float4*)c0;
    const float4 a1 = *(const float4*)(c0 + 4);
    const float4 s0 = *(const float4*)c1;
    const float4 s1 = *(const float4*)(c1 + 4);
    unsigned short* dst = B + ((size_t)j * IN + i) * 16;
    *(uint4*)dst       = make_uint4(packbf(a0.x, a0.y), packbf(a0.z, a0.w),
                                    packbf(a1.x, a1.y), packbf(a1.z, a1.w));
    *(uint4*)(dst + 8) = make_uint4(packbf(s0.x, s0.y), packbf(s0.z, s0.w),
                                    packbf(s1.x, s1.y), packbf(s1.z, s1.w));
}

// x [4096][768] f32 -> A1 [4096][768*16] bf16 (features of the input layer)
__global__ void feats_x_kernel(const float* __restrict__ x, unsigned short* __restrict__ A) {
    const size_t idx = (size_t)blockIdx.x * 256 + threadIdx.x;   // (b,i) linear
    unsigned o[8];
    feats16(x[idx], o);
    unsigned short* dst = A + idx * 16;
    *(uint4*)dst       = make_uint4(o[0], o[1], o[2], o[3]);
    *(uint4*)(dst + 8) = make_uint4(o[4], o[5], o[6], o[7]);
}

// Deterministic split-K reduce + feature epilogue, 4 (b,j) per thread (float4 path).
template <int N, int KSPLIT>
__global__ void reduce_feats(const float* __restrict__ P, const float* __restrict__ bias,
                             unsigned short* __restrict__ A) {
    const size_t idx = ((size_t)blockIdx.x * 256 + threadIdx.x) * 4;  // (b,j) linear, x4
    const int j = (int)(idx % N);                                      // N % 4 == 0
    float4 s = *(const float4*)(P + idx);
    #pragma unroll
    for (int z = 1; z < KSPLIT; ++z) {
        const float4 v = *(const float4*)(P + (size_t)z * BATCH * N + idx);
        s.x += v.x; s.y += v.y; s.z += v.z; s.w += v.w;
    }
    const float4 bv = *(const float4*)(bias + j);
    const float y[4] = { s.x + bv.x, s.y + bv.y, s.z + bv.z, s.w + bv.w };
    unsigned short* dst = A + idx * 16;
    #pragma unroll
    for (int e = 0; e < 4; ++e) {
        unsigned o[8];
        feats16(y[e], o);
        *(uint4*)(dst + e * 16)     = make_uint4(o[0], o[1], o[2], o[3]);
        *(uint4*)(dst + e * 16 + 8) = make_uint4(o[4], o[5], o[6], o[7]);
    }
}

// Deterministic split-K reduction: out[b][j] = sum_z P[z][b][j] + bias[j].
template <int N, int KSPLIT>
__global__ void reduce_out(const float* __restrict__ P, const float* __restrict__ bias,
                           float* __restrict__ out) {
    const size_t idx = ((size_t)blockIdx.x * 256 + threadIdx.x) * 4;   // float4 granule
    const int j = (int)(idx % N);                                       // N % 4 == 0
    float4 s = *(const float4*)(P + idx);
    #pragma unroll
    for (int z = 1; z < KSPLIT; ++z) {
        const float4 v = *(const float4*)(P + (size_t)z * BATCH * N + idx);
        s.x += v.x; s.y += v.y; s.z += v.z; s.w += v.w;
    }
    const float4 bv = *(const float4*)(bias + j);
    s.x += bv.x; s.y += bv.y; s.z += bv.z; s.w += bv.w;
    *(float4*)(out + idx) = s;
}

// ------------- main bf16 GEMM: 256x256, 8 waves, 4-phase + counted lgkm + B-frag carry -------------
// v11 = v9 (verified: 47.7% MfmaUtil, no spill) + ONE change: the 8 B-frag ds_reads for tile
// t+1 are issued in P4 AFTER the vmcnt(6)+barrier certify point (cross-wave safe: reads of
// freshly staged data only ever happen post-certify-barrier -- the round-7/8 lesson) and are
// carried in bF0/bF1 (double-body swap, compile-time indexing per rule #20). P1 then issues
// only aFa[8], and its lgkmcnt(4) retire-set (carried bN + aFa01) is mostly pre-drained
// under P4's MFMA + close barrier. Addressing stays v9's direct &As[...] style (round-10
// lesson: hoisted generic pointers risk flat_load, which corrupts BOTH waitcnt counters).
// Waits: P1 lgkm(4) [bN+aFa01]; P2 lgkm(8) [aFa23]; P3 lgkm(4) [aFb45]; P4 lgkm(8) [aFb67].
template <int K, int N, int KSPLIT>
__global__ __launch_bounds__(512, 2)
void kan_gemm(const unsigned short* __restrict__ A,
              const unsigned short* __restrict__ B,
              float* __restrict__ P)
{
    __shared__ unsigned short As[2 * 2 * 128 * 64];   // 64 KB
    __shared__ unsigned short Bs[2 * 2 * 128 * 64];   // 64 KB

    const int tid  = threadIdx.x;
    const int lane = tid & 63;
    const int wave = tid >> 6;          // 0..7
    const int wm   = wave >> 2;         // 0..1: wave row -> 128 batch rows
    const int wn   = wave & 3;          // 0..3: wave col -> 64 out cols
    const int fr   = lane & 15;
    const int fq   = lane >> 4;

    // 2-D XCD chunk swizzle over 256-tiles (round-4 verified).
    constexpr int NBX = BATCH / 256;
    constexpr int NBY = N / 256;
    constexpr int NWG = NBX * NBY;
    constexpr int S   = NWG / 8;
    constexpr int CC  = (NBY >= 8) ? 8 : NBY;
    constexpr int CR  = S / CC;
    constexpr int GR  = NBX / CR;
    const int wg  = blockIdx.y * NBX + blockIdx.x;
    const int xc  = wg & 7;
    const int ci  = wg >> 3;
    const int row0 = ((xc % GR) * CR + ci % CR) * 256;
    const int col0 = ((xc / GR) * CC + ci / CR) * 256;

    constexpr int KCH = K / KSPLIT;
    const int kt0 = ((int)blockIdx.z * KCH) >> 6;
    const int nt  = KCH >> 6;           // even for all layers (96/256/64 per z)

    const int srow = lane >> 3;                   // 0..7 within the wave's 8-row stripe
    const int scol = ((lane & 7) ^ srow) * 16;    // pre-swizzled global 16B chunk (bytes)

    auto STA = [&](int b, int h, int kt) {
        #pragma unroll
        for (int r2 = 0; r2 < 2; ++r2)
            gload_lds16((const char*)A +
                        ((size_t)(row0 + h * 128 + r2 * 64 + wave * 8 + srow) * K + (size_t)kt * 64) * 2 + scol,
                        (char*)&As[((b * 2 + h) * 128 + r2 * 64 + wave * 8) * 64]);
    };
    auto STB = [&](int b, int h, int kt) {
        #pragma unroll
        for (int r2 = 0; r2 < 2; ++r2)
            gload_lds16((const char*)B +
                        ((size_t)(col0 + h * 128 + r2 * 64 + wave * 8 + srow) * K + (size_t)kt * 64) * 2 + scol,
                        (char*)&Bs[((b * 2 + h) * 128 + r2 * 64 + wave * 8) * 64]);
    };
    auto LDA = [&](int b, int m, int ks) -> bf16x8 {
        return *(const bf16x8*)&As[((b * 2 + wm) * 128 + m * 16 + fr) * 64 +
                                   (((ks * 4 + fq) ^ (fr & 7)) << 3)];
    };
    auto LDB = [&](int b, int n, int ks) -> bf16x8 {
        return *(const bf16x8*)&Bs[((b * 2 + (wn >> 1)) * 128 + (wn & 1) * 64 + n * 16 + fr) * 64 +
                                   (((ks * 4 + fq) ^ (fr & 7)) << 3)];
    };

    f32x4 acc[8][4] = {};
    bf16x8 bF0[8], bF1[8];              // carried B-frags (current / next tile), swap by parity

    // Prologue: tile0 all 4 halves + tile1 {B0,A0,A1}; certify; BARRIER; pre-read bF0(tile0).
    STA(0, 0, kt0); STA(0, 1, kt0); STB(0, 0, kt0); STB(0, 1, kt0);
    STB(1, 0, kt0 + 1); STA(1, 0, kt0 + 1); STA(1, 1, kt0 + 1);
    asm volatile("s_waitcnt vmcnt(6)" ::: "memory");
    __builtin_amdgcn_sched_barrier(0);
    __builtin_amdgcn_s_barrier();                      // ALL waves' tile-0 loads certified
    __builtin_amdgcn_sched_barrier(0);
    #pragma unroll
    for (int n = 0; n < 4; ++n) { bF0[n * 2] = LDB(0, n, 0); bF0[n * 2 + 1] = LDB(0, n, 1); }
    __builtin_amdgcn_sched_barrier(0);

    auto body = [&](int t, int b, bf16x8 (&bFc)[8], bf16x8 (&bFn)[8]) {
        const int kt = kt0 + t;
        bf16x8 aFa[8], aFb[8];

        // ---- P1: issue aFa m0-1, [pin], aFa m2-3; stage B1(t+1) -> buf^1
        #pragma unroll
        for (int mm = 0; mm < 2; ++mm) { aFa[mm * 2] = LDA(b, mm, 0); aFa[mm * 2 + 1] = LDA(b, mm, 1); }
        __builtin_amdgcn_sched_barrier(0);   // oldest-12 boundary (carried bN + aFa m0-1)
        #pragma unroll
        for (int mm = 2; mm < 4; ++mm) { aFa[mm * 2] = LDA(b, mm, 0); aFa[mm * 2 + 1] = LDA(b, mm, 1); }
        if (t + 1 < nt) STB(b ^ 1, 1, kt + 1);
        __builtin_amdgcn_sched_barrier(0);
        __builtin_amdgcn_s_barrier();
        asm volatile("s_waitcnt lgkmcnt(4)" ::: "memory");   // retire bN(carried) + aFa m0-1
        __builtin_amdgcn_sched_barrier(0);
        __builtin_amdgcn_s_setprio(1);
        #pragma unroll
        for (int ks = 0; ks < 2; ++ks)
            #pragma unroll
            for (int mm = 0; mm < 2; ++mm)
                #pragma unroll
                for (int n = 0; n < 4; ++n)
                    acc[mm][n] = __builtin_amdgcn_mfma_f32_16x16x32_bf16(
                        aFa[mm * 2 + ks], bFc[n * 2 + ks], acc[mm][n], 0, 0, 0);
        __builtin_amdgcn_s_setprio(0);

        // ---- P2: issue aFb m4-5, [pin], aFb m6-7; stage B0(t+2) -> buf b
        #pragma unroll
        for (int mm = 0; mm < 2; ++mm) { aFb[mm * 2] = LDA(b, 4 + mm, 0); aFb[mm * 2 + 1] = LDA(b, 4 + mm, 1); }
        __builtin_amdgcn_sched_barrier(0);   // aFb m4-5 | m6-7 boundary
        #pragma unroll
        for (int mm = 2; mm < 4; ++mm) { aFb[mm * 2] = LDA(b, 4 + mm, 0); aFb[mm * 2 + 1] = LDA(b, 4 + mm, 1); }
        if (t + 2 < nt) STB(b, 0, kt + 2);
        __builtin_amdgcn_sched_barrier(0);
        __builtin_amdgcn_s_barrier();
        asm volatile("s_waitcnt lgkmcnt(8)" ::: "memory");   // retire aFa m2-3
        __builtin_amdgcn_sched_barrier(0);
        __builtin_amdgcn_s_setprio(1);
        #pragma unroll
        for (int ks = 0; ks < 2; ++ks)
            #pragma unroll
            for (int mm = 0; mm < 2; ++mm)
                #pragma unroll
                for (int n = 0; n < 4; ++n)
                    acc[2 + mm][n] = __builtin_amdgcn_mfma_f32_16x16x32_bf16(
                        aFa[(2 + mm) * 2 + ks], bFc[n * 2 + ks], acc[2 + mm][n], 0, 0, 0);
        __builtin_amdgcn_s_setprio(0);

        // ---- P3: stage A0(t+2) -> buf b; MFMA m4-5
        if (t + 2 < nt) STA(b, 0, kt + 2);
        __builtin_amdgcn_sched_barrier(0);
        __builtin_amdgcn_s_barrier();
        asm volatile("s_waitcnt lgkmcnt(4)" ::: "memory");   // retire aFb m4-5
        __builtin_amdgcn_sched_barrier(0);
        __builtin_amdgcn_s_setprio(1);
        #pragma unroll
        for (int ks = 0; ks < 2; ++ks)
            #pragma unroll
            for (int mm = 0; mm < 2; ++mm)
                #pragma unroll
                for (int n = 0; n < 4; ++n)
                    acc[4 + mm][n] = __builtin_amdgcn_mfma_f32_16x16x32_bf16(
                        aFb[mm * 2 + ks], bFc[n * 2 + ks], acc[4 + mm][n], 0, 0, 0);
        __builtin_amdgcn_s_setprio(0);

        // ---- P4: stage A1(t+2); vmcnt(6) certifies t+1; BARRIER; pre-read bFn(t+1); MFMA m6-7
        if (t + 2 < nt) {
            STA(b, 1, kt + 2);
            asm volatile("s_waitcnt vmcnt(6)" ::: "memory");
        } else {
            asm volatile("s_waitcnt vmcnt(0)" ::: "memory");
        }
        __builtin_amdgcn_sched_barrier(0);
        __builtin_amdgcn_s_barrier();       // ALL waves' t+1 loads certified -> reads safe
        __builtin_amdgcn_sched_barrier(0);
        if (t + 1 < nt) {
            #pragma unroll
            for (int n = 0; n < 4; ++n) { bFn[n * 2] = LDB(b ^ 1, n, 0); bFn[n * 2 + 1] = LDB(b ^ 1, n, 1); }
            __builtin_amdgcn_sched_barrier(0);
            asm volatile("s_waitcnt lgkmcnt(8)" ::: "memory");   // retire aFb m6-7; bFn stays in flight
        } else {
            asm volatile("s_waitcnt lgkmcnt(0)" ::: "memory");
        }
        __builtin_amdgcn_sched_barrier(0);
        __builtin_amdgcn_s_setprio(1);
        #pragma unroll
        for (int ks = 0; ks < 2; ++ks)
            #pragma unroll
            for (int mm = 0; mm < 2; ++mm)
                #pragma unroll
                for (int n = 0; n < 4; ++n)
                    acc[6 + mm][n] = __builtin_amdgcn_mfma_f32_16x16x32_bf16(
                        aFb[(2 + mm) * 2 + ks], bFc[n * 2 + ks], acc[6 + mm][n], 0, 0, 0);
        __builtin_amdgcn_s_setprio(0);
        __builtin_amdgcn_sched_barrier(0);
        __builtin_amdgcn_s_barrier();       // P4 close: protects next tile's P1 stage
    };

    #pragma unroll 1
    for (int t = 0; t < nt; t += 2) {
        body(t,     0, bF0, bF1);
        body(t + 1, 1, bF1, bF0);
    }

    // Epilogue: split-K partial plane. C/D layout: col = lane&15, row = (lane>>4)*4+reg.
    float* Pz = P + (size_t)blockIdx.z * BATCH * N;
    #pragma unroll
    for (int m = 0; m < 8; ++m) {
        const int gr0 = row0 + wm * 128 + m * 16 + fq * 4;
        #pragma unroll
        for (int n = 0; n < 4; ++n) {
            const int gc = col0 + wn * 64 + n * 16 + fr;
            #pragma unroll
            for (int q = 0; q < 4; ++q)
                Pz[(size_t)(gr0 + q) * N + gc] = acc[m][n][q];
        }
    }
}

extern "C" void kernel_launch(void* const* d_in, const int* in_sizes, int n_in,
                              void* d_out, int out_size, void* d_ws, size_t ws_size,
                              hipStream_t stream) {
    (void)in_sizes; (void)n_in; (void)ws_size; (void)out_size;
    const float* x  = (const float*)d_in[0];   // [4096][768]
    const float* C1 = (const float*)d_in[1];   // [2][2048][768][8]
    const float* b1 = (const float*)d_in[2];   // [2048]
    const float* C2 = (const float*)d_in[3];   // [2][2048][2048][8]
    const float* b2 = (const float*)d_in[4];   // [2048]
    const float* C3 = (const float*)d_in[5];   // [2][512][2048][8]
    const float* b3 = (const float*)d_in[6];   // [512]
    float* out = (float*)d_out;                // [4096][512]

    // Workspace layout, lifetime-aliased (proven). Peak 554 MB.
    char* ws = (char*)d_ws;
    const size_t SZ_A1  = (size_t)4096 * 12288 * 2;      // 100,663,296
    const size_t SZ_B1  = (size_t)2048 * 12288 * 2;      //  50,331,648
    const size_t SZ_P12 = (size_t)2 * 4096 * 2048 * 4;   //  67,108,864
    const size_t SZ_A2  = (size_t)4096 * 32768 * 2;      // 268,435,456
    unsigned short* A1 = (unsigned short*)(ws);
    unsigned short* B1 = (unsigned short*)(ws + SZ_A1);
    float*          P1 = (float*)(ws + SZ_A1 + SZ_B1);
    unsigned short* A2 = (unsigned short*)(ws + SZ_A1 + SZ_B1 + SZ_P12);
    unsigned short* B2 = (unsigned short*)(ws);                           // aliases dead A1+B1
    float*          P2 = (float*)(ws + SZ_A1 + SZ_B1 + SZ_P12 + SZ_A2);
    unsigned short* A3 = (unsigned short*)(ws);                           // aliases dead B2/P1
    unsigned short* B3 = (unsigned short*)(ws + SZ_A2);
    float*          P3 = (float*)(ws + SZ_A2 + (size_t)512 * 32768 * 2);

    // ---- layer 1: (4096 x 12288) x (2048 x 12288)^T, split-K x2 -> feats -> A2
    conv_C<768, 2048><<<dim3(768 / 256, 2048), 256, 0, stream>>>(C1, B1);
    feats_x_kernel<<<dim3((4096 * 768) / 256), 256, 0, stream>>>(x, A1);
    kan_gemm<12288, 2048, 2><<<dim3(16, 8, 2), 512, 0, stream>>>(A1, B1, P1);
    reduce_feats<2048, 2><<<dim3((BATCH * 2048 / 4) / 256), 256, 0, stream>>>(P1, b1, A2);

    // ---- layer 2: (4096 x 32768) x (2048 x 32768)^T, split-K x2 -> feats -> A3
    conv_C<2048, 2048><<<dim3(2048 / 256, 2048), 256, 0, stream>>>(C2, B2);
    kan_gemm<32768, 2048, 2><<<dim3(16, 8, 2), 512, 0, stream>>>(A2, B2, P2);
    reduce_feats<2048, 2><<<dim3((BATCH * 2048 / 4) / 256), 256, 0, stream>>>(P2, b2, A3);

    // ---- layer 3: (4096 x 32768) x (512 x 32768)^T, split-K x8, deterministic reduce
    conv_C<2048, 512><<<dim3(2048 / 256, 512), 256, 0, stream>>>(C3, B3);
    kan_gemm<32768, 512, 8><<<dim3(16, 2, 8), 512, 0, stream>>>(A3, B3, P3);
    reduce_out<512, 8><<<dim3((BATCH * 512 / 4) / 256), 256, 0, stream>>>(P3, b3, out);
}

// Round 12
// 1160.378 us; speedup vs baseline: 1.9113x; 1.9113x over previous
//
#include <hip/hip_runtime.h>

#define BATCH 4096

typedef __attribute__((ext_vector_type(8))) short bf16x8;
typedef __attribute__((ext_vector_type(4))) float f32x4;

// Manual RNE float->bf16 (round half to even), matches HW/NumPy for normal finite values.
__device__ __forceinline__ unsigned short f2bf(float f) {
    union { float f; unsigned u; } v; v.f = f;
    unsigned r = v.u + 0x7fffu + ((v.u >> 16) & 1u);
    return (unsigned short)(r >> 16);
}
__device__ __forceinline__ unsigned packbf(float a, float b) {
    return (unsigned)f2bf(a) | ((unsigned)f2bf(b) << 16);
}

// 16 features for one x: o[0..3] = cos(1x..8x) pairs, o[4..7] = sin(1x..8x) pairs (bf16x2).
__device__ __forceinline__ void feats16(float x, unsigned o[8]) {
    float c1 = __cosf(x), s1 = __sinf(x);
    float cs[8], sn[8];
    cs[0] = c1; sn[0] = s1;
    #pragma unroll
    for (int k = 1; k < 8; ++k) {
        cs[k] = c1 * cs[k-1] - s1 * sn[k-1];
        sn[k] = s1 * cs[k-1] + c1 * sn[k-1];
    }
    #pragma unroll
    for (int k = 0; k < 4; ++k) {
        o[k]     = packbf(cs[2*k], cs[2*k+1]);
        o[4 + k] = packbf(sn[2*k], sn[2*k+1]);
    }
}

// Async global->LDS, 16 B per lane. LDS dest is wave-uniform base; HW adds lane*16.
__device__ __forceinline__ void gload_lds16(const void* g, void* l) {
    __builtin_amdgcn_global_load_lds(
        (__attribute__((address_space(1))) void*)(g),
        (__attribute__((address_space(3))) void*)(l), 16, 0, 0);
}

// ---------------- one-shot precompute kernels ----------------

// C [2][OUT][IN][8] f32  ->  B [OUT][IN*16] bf16, k = i*16 + d*8 + g
template <int IN, int OUT>
__global__ void conv_C(const float* __restrict__ C, unsigned short* __restrict__ B) {
    const int i = blockIdx.x * 256 + threadIdx.x;
    const int j = blockIdx.y;
    const float* c0 = C + ((size_t)j * IN + i) * 8;            // d=0 (cos) plane
    const float* c1 = c0 + (size_t)OUT * IN * 8;               // d=1 (sin) plane
    const float4 a0 = *(const float4*)c0;
    const float4 a1 = *(const float4*)(c0 + 4);
    const float4 s0 = *(const float4*)c1;
    const float4 s1 = *(const float4*)(c1 + 4);
    unsigned short* dst = B + ((size_t)j * IN + i) * 16;
    *(uint4*)dst       = make_uint4(packbf(a0.x, a0.y), packbf(a0.z, a0.w),
                                    packbf(a1.x, a1.y), packbf(a1.z, a1.w));
    *(uint4*)(dst + 8) = make_uint4(packbf(s0.x, s0.y), packbf(s0.z, s0.w),
                                    packbf(s1.x, s1.y), packbf(s1.z, s1.w));
}

// x [4096][768] f32 -> A1 [4096][768*16] bf16 (features of the input layer)
__global__ void feats_x_kernel(const float* __restrict__ x, unsigned short* __restrict__ A) {
    const size_t idx = (size_t)blockIdx.x * 256 + threadIdx.x;   // (b,i) linear
    unsigned o[8];
    feats16(x[idx], o);
    unsigned short* dst = A + idx * 16;
    *(uint4*)dst       = make_uint4(o[0], o[1], o[2], o[3]);
    *(uint4*)(dst + 8) = make_uint4(o[4], o[5], o[6], o[7]);
}

// Deterministic split-K reduce + feature epilogue, 4 (b,j) per thread (float4 path).
template <int N, int KSPLIT>
__global__ void reduce_feats(const float* __restrict__ P, const float* __restrict__ bias,
                             unsigned short* __restrict__ A) {
    const size_t idx = ((size_t)blockIdx.x * 256 + threadIdx.x) * 4;  // (b,j) linear, x4
    const int j = (int)(idx % N);                                      // N % 4 == 0
    float4 s = *(const float4*)(P + idx);
    #pragma unroll
    for (int z = 1; z < KSPLIT; ++z) {
        const float4 v = *(const float4*)(P + (size_t)z * BATCH * N + idx);
        s.x += v.x; s.y += v.y; s.z += v.z; s.w += v.w;
    }
    const float4 bv = *(const float4*)(bias + j);
    const float y[4] = { s.x + bv.x, s.y + bv.y, s.z + bv.z, s.w + bv.w };
    unsigned short* dst = A + idx * 16;
    #pragma unroll
    for (int e = 0; e < 4; ++e) {
        unsigned o[8];
        feats16(y[e], o);
        *(uint4*)(dst + e * 16)     = make_uint4(o[0], o[1], o[2], o[3]);
        *(uint4*)(dst + e * 16 + 8) = make_uint4(o[4], o[5], o[6], o[7]);
    }
}

// Deterministic split-K reduction: out[b][j] = sum_z P[z][b][j] + bias[j].
template <int N, int KSPLIT>
__global__ void reduce_out(const float* __restrict__ P, const float* __restrict__ bias,
                           float* __restrict__ out) {
    const size_t idx = ((size_t)blockIdx.x * 256 + threadIdx.x) * 4;   // float4 granule
    const int j = (int)(idx % N);                                       // N % 4 == 0
    float4 s = *(const float4*)(P + idx);
    #pragma unroll
    for (int z = 1; z < KSPLIT; ++z) {
        const float4 v = *(const float4*)(P + (size_t)z * BATCH * N + idx);
        s.x += v.x; s.y += v.y; s.z += v.z; s.w += v.w;
    }
    const float4 bv = *(const float4*)(bias + j);
    s.x += bv.x; s.y += bv.y; s.z += bv.z; s.w += bv.w;
    *(float4*)(out + idx) = s;
}

// ------------- main bf16 GEMM: 256x256 tile, 8 waves, 4-phase + counted lgkmcnt -------------
// v12 == v9 verbatim (the session's verified best: layer-2 517 us, MfmaUtil 47.7%, no spill).
// Reads placed 16/8/0/0 (P1: bF[8]+aFa[8]; P2: aFb[8]); each phase waits only for its own
// operands -- P1 lgkmcnt(4), P2 lgkmcnt(8), P3 lgkmcnt(4), P4 lgkmcnt(0) -- so the next
// phase's already-issued reads drain under the current MFMA cluster. Issue order pinned with
// sched_barrier(0) between read groups; sched_barrier(0) after every wait (rule #18).
// NOTE (rounds 8/10/11): any loop-carried fragment registers on top of acc[8][4] (=128 VGPR)
// spill to scratch (WRITE_SIZE balloons) or, with hoisted generic pointers, degrade to
// flat_load (corrupts both waitcnt counters). Do not re-attempt register-carried pipelining
// in this structure.
template <int K, int N, int KSPLIT>
__global__ __launch_bounds__(512, 2)
void kan_gemm(const unsigned short* __restrict__ A,
              const unsigned short* __restrict__ B,
              float* __restrict__ P)
{
    __shared__ unsigned short As[2 * 2 * 128 * 64];   // 64 KB
    __shared__ unsigned short Bs[2 * 2 * 128 * 64];   // 64 KB

    const int tid  = threadIdx.x;
    const int lane = tid & 63;
    const int wave = tid >> 6;          // 0..7
    const int wm   = wave >> 2;         // 0..1: wave row -> 128 batch rows
    const int wn   = wave & 3;          // 0..3: wave col -> 64 out cols
    const int fr   = lane & 15;
    const int fq   = lane >> 4;

    // 2-D XCD chunk swizzle over 256-tiles (round-4 verified).
    constexpr int NBX = BATCH / 256;
    constexpr int NBY = N / 256;
    constexpr int NWG = NBX * NBY;
    constexpr int S   = NWG / 8;
    constexpr int CC  = (NBY >= 8) ? 8 : NBY;
    constexpr int CR  = S / CC;
    constexpr int GR  = NBX / CR;
    const int wg  = blockIdx.y * NBX + blockIdx.x;
    const int xc  = wg & 7;
    const int ci  = wg >> 3;
    const int row0 = ((xc % GR) * CR + ci % CR) * 256;
    const int col0 = ((xc / GR) * CC + ci / CR) * 256;

    constexpr int KCH = K / KSPLIT;
    const int kt0 = ((int)blockIdx.z * KCH) >> 6;
    const int nt  = KCH >> 6;

    const int srow = lane >> 3;                   // 0..7 within the wave's 8-row stripe
    const int scol = ((lane & 7) ^ srow) * 16;    // pre-swizzled global 16B chunk (bytes)

    auto STA = [&](int b, int h, int kt) {
        #pragma unroll
        for (int r2 = 0; r2 < 2; ++r2)
            gload_lds16((const char*)A +
                        ((size_t)(row0 + h * 128 + r2 * 64 + wave * 8 + srow) * K + (size_t)kt * 64) * 2 + scol,
                        (char*)&As[((b * 2 + h) * 128 + r2 * 64 + wave * 8) * 64]);
    };
    auto STB = [&](int b, int h, int kt) {
        #pragma unroll
        for (int r2 = 0; r2 < 2; ++r2)
            gload_lds16((const char*)B +
                        ((size_t)(col0 + h * 128 + r2 * 64 + wave * 8 + srow) * K + (size_t)kt * 64) * 2 + scol,
                        (char*)&Bs[((b * 2 + h) * 128 + r2 * 64 + wave * 8) * 64]);
    };
    auto LDA = [&](int b, int m, int ks) -> bf16x8 {
        return *(const bf16x8*)&As[((b * 2 + wm) * 128 + m * 16 + fr) * 64 +
                                   (((ks * 4 + fq) ^ (fr & 7)) << 3)];
    };
    auto LDB = [&](int b, int n, int ks) -> bf16x8 {
        return *(const bf16x8*)&Bs[((b * 2 + (wn >> 1)) * 128 + (wn & 1) * 64 + n * 16 + fr) * 64 +
                                   (((ks * 4 + fq) ^ (fr & 7)) << 3)];
    };

    f32x4 acc[8][4] = {};

    // Prologue: tile0 all 4 halves + tile1 {B0,A0,A1} (B1(t=1) staged in tile0's P1).
    STA(0, 0, kt0); STA(0, 1, kt0); STB(0, 0, kt0); STB(0, 1, kt0);
    STB(1, 0, kt0 + 1); STA(1, 0, kt0 + 1); STA(1, 1, kt0 + 1);
    asm volatile("s_waitcnt vmcnt(6)" ::: "memory");
    __builtin_amdgcn_s_barrier();
    __builtin_amdgcn_sched_barrier(0);

    #pragma unroll 1
    for (int t = 0; t < nt; ++t) {
        const int b  = t & 1;
        const int kt = kt0 + t;
        bf16x8 bF[8], aFa[8], aFb[8];

        // ---- P1: issue bF[8] + aFa m0-1, [pin], aFa m2-3; stage B1(t+1) -> buf^1
        #pragma unroll
        for (int n = 0; n < 4; ++n) { bF[n * 2] = LDB(b, n, 0); bF[n * 2 + 1] = LDB(b, n, 1); }
        #pragma unroll
        for (int mm = 0; mm < 2; ++mm) { aFa[mm * 2] = LDA(b, mm, 0); aFa[mm * 2 + 1] = LDA(b, mm, 1); }
        __builtin_amdgcn_sched_barrier(0);   // oldest-12 boundary (bF + aFa m0-1)
        #pragma unroll
        for (int mm = 2; mm < 4; ++mm) { aFa[mm * 2] = LDA(b, mm, 0); aFa[mm * 2 + 1] = LDA(b, mm, 1); }
        if (t + 1 < nt) STB(b ^ 1, 1, kt + 1);
        __builtin_amdgcn_sched_barrier(0);
        __builtin_amdgcn_s_barrier();
        asm volatile("s_waitcnt lgkmcnt(4)" ::: "memory");   // retire bF + aFa m0-1
        __builtin_amdgcn_sched_barrier(0);
        __builtin_amdgcn_s_setprio(1);
        #pragma unroll
        for (int ks = 0; ks < 2; ++ks)
            #pragma unroll
            for (int mm = 0; mm < 2; ++mm)
                #pragma unroll
                for (int n = 0; n < 4; ++n)
                    acc[mm][n] = __builtin_amdgcn_mfma_f32_16x16x32_bf16(
                        aFa[mm * 2 + ks], bF[n * 2 + ks], acc[mm][n], 0, 0, 0);
        __builtin_amdgcn_s_setprio(0);

        // ---- P2: issue aFb m4-5, [pin], aFb m6-7; stage B0(t+2) -> buf b
        #pragma unroll
        for (int mm = 0; mm < 2; ++mm) { aFb[mm * 2] = LDA(b, 4 + mm, 0); aFb[mm * 2 + 1] = LDA(b, 4 + mm, 1); }
        __builtin_amdgcn_sched_barrier(0);   // aFb m4-5 | m6-7 boundary
        #pragma unroll
        for (int mm = 2; mm < 4; ++mm) { aFb[mm * 2] = LDA(b, 4 + mm, 0); aFb[mm * 2 + 1] = LDA(b, 4 + mm, 1); }
        if (t + 2 < nt) STB(b, 0, kt + 2);
        __builtin_amdgcn_sched_barrier(0);
        __builtin_amdgcn_s_barrier();
        asm volatile("s_waitcnt lgkmcnt(8)" ::: "memory");   // retire aFa m2-3
        __builtin_amdgcn_sched_barrier(0);
        __builtin_amdgcn_s_setprio(1);
        #pragma unroll
        for (int ks = 0; ks < 2; ++ks)
            #pragma unroll
            for (int mm = 0; mm < 2; ++mm)
                #pragma unroll
                for (int n = 0; n < 4; ++n)
                    acc[2 + mm][n] = __builtin_amdgcn_mfma_f32_16x16x32_bf16(
                        aFa[(2 + mm) * 2 + ks], bF[n * 2 + ks], acc[2 + mm][n], 0, 0, 0);
        __builtin_amdgcn_s_setprio(0);

        // ---- P3: stage A0(t+2) -> buf b; MFMA m4-5 (aFb m4-5 retire via lgkmcnt(4))
        if (t + 2 < nt) STA(b, 0, kt + 2);
        __builtin_amdgcn_sched_barrier(0);
        __builtin_amdgcn_s_barrier();
        asm volatile("s_waitcnt lgkmcnt(4)" ::: "memory");   // retire aFb m4-5
        __builtin_amdgcn_sched_barrier(0);
        __builtin_amdgcn_s_setprio(1);
        #pragma unroll
        for (int ks = 0; ks < 2; ++ks)
            #pragma unroll
            for (int mm = 0; mm < 2; ++mm)
                #pragma unroll
                for (int n = 0; n < 4; ++n)
                    acc[4 + mm][n] = __builtin_amdgcn_mfma_f32_16x16x32_bf16(
                        aFb[mm * 2 + ks], bF[n * 2 + ks], acc[4 + mm][n], 0, 0, 0);
        __builtin_amdgcn_s_setprio(0);

        // ---- P4: stage A1(t+2); counted vmcnt certifies t+1; MFMA m6-7
        if (t + 2 < nt) {
            STA(b, 1, kt + 2);
            asm volatile("s_waitcnt vmcnt(6)" ::: "memory");
        } else {
            asm volatile("s_waitcnt vmcnt(0)" ::: "memory");
        }
        __builtin_amdgcn_sched_barrier(0);
        __builtin_amdgcn_s_barrier();
        asm volatile("s_waitcnt lgkmcnt(0)" ::: "memory");   // retire aFb m6-7
        __builtin_amdgcn_sched_barrier(0);
        __builtin_amdgcn_s_setprio(1);
        #pragma unroll
        for (int ks = 0; ks < 2; ++ks)
            #pragma unroll
            for (int mm = 0; mm < 2; ++mm)
                #pragma unroll
                for (int n = 0; n < 4; ++n)
                    acc[6 + mm][n] = __builtin_amdgcn_mfma_f32_16x16x32_bf16(
                        aFb[(2 + mm) * 2 + ks], bF[n * 2 + ks], acc[6 + mm][n], 0, 0, 0);
        __builtin_amdgcn_s_setprio(0);
        __builtin_amdgcn_sched_barrier(0);
        __builtin_amdgcn_s_barrier();       // P4 close: protects next tile's P1 stage
    }

    // Epilogue: split-K partial plane. C/D layout: col = lane&15, row = (lane>>4)*4+reg.
    float* Pz = P + (size_t)blockIdx.z * BATCH * N;
    #pragma unroll
    for (int m = 0; m < 8; ++m) {
        const int gr0 = row0 + wm * 128 + m * 16 + fq * 4;
        #pragma unroll
        for (int n = 0; n < 4; ++n) {
            const int gc = col0 + wn * 64 + n * 16 + fr;
            #pragma unroll
            for (int q = 0; q < 4; ++q)
                Pz[(size_t)(gr0 + q) * N + gc] = acc[m][n][q];
        }
    }
}

extern "C" void kernel_launch(void* const* d_in, const int* in_sizes, int n_in,
                              void* d_out, int out_size, void* d_ws, size_t ws_size,
                              hipStream_t stream) {
    (void)in_sizes; (void)n_in; (void)ws_size; (void)out_size;
    const float* x  = (const float*)d_in[0];   // [4096][768]
    const float* C1 = (const float*)d_in[1];   // [2][2048][768][8]
    const float* b1 = (const float*)d_in[2];   // [2048]
    const float* C2 = (const float*)d_in[3];   // [2][2048][2048][8]
    const float* b2 = (const float*)d_in[4];   // [2048]
    const float* C3 = (const float*)d_in[5];   // [2][512][2048][8]
    const float* b3 = (const float*)d_in[6];   // [512]
    float* out = (float*)d_out;                // [4096][512]

    // Workspace layout, lifetime-aliased (proven). Peak 554 MB.
    char* ws = (char*)d_ws;
    const size_t SZ_A1  = (size_t)4096 * 12288 * 2;      // 100,663,296
    const size_t SZ_B1  = (size_t)2048 * 12288 * 2;      //  50,331,648
    const size_t SZ_P12 = (size_t)2 * 4096 * 2048 * 4;   //  67,108,864
    const size_t SZ_A2  = (size_t)4096 * 32768 * 2;      // 268,435,456
    unsigned short* A1 = (unsigned short*)(ws);
    unsigned short* B1 = (unsigned short*)(ws + SZ_A1);
    float*          P1 = (float*)(ws + SZ_A1 + SZ_B1);
    unsigned short* A2 = (unsigned short*)(ws + SZ_A1 + SZ_B1 + SZ_P12);
    unsigned short* B2 = (unsigned short*)(ws);                           // aliases dead A1+B1
    float*          P2 = (float*)(ws + SZ_A1 + SZ_B1 + SZ_P12 + SZ_A2);
    unsigned short* A3 = (unsigned short*)(ws);                           // aliases dead B2/P1
    unsigned short* B3 = (unsigned short*)(ws + SZ_A2);
    float*          P3 = (float*)(ws + SZ_A2 + (size_t)512 * 32768 * 2);

    // ---- layer 1: (4096 x 12288) x (2048 x 12288)^T, split-K x2 -> feats -> A2
    conv_C<768, 2048><<<dim3(768 / 256, 2048), 256, 0, stream>>>(C1, B1);
    feats_x_kernel<<<dim3((4096 * 768) / 256), 256, 0, stream>>>(x, A1);
    kan_gemm<12288, 2048, 2><<<dim3(16, 8, 2), 512, 0, stream>>>(A1, B1, P1);
    reduce_feats<2048, 2><<<dim3((BATCH * 2048 / 4) / 256), 256, 0, stream>>>(P1, b1, A2);

    // ---- layer 2: (4096 x 32768) x (2048 x 32768)^T, split-K x2 -> feats -> A3
    conv_C<2048, 2048><<<dim3(2048 / 256, 2048), 256, 0, stream>>>(C2, B2);
    kan_gemm<32768, 2048, 2><<<dim3(16, 8, 2), 512, 0, stream>>>(A2, B2, P2);
    reduce_feats<2048, 2><<<dim3((BATCH * 2048 / 4) / 256), 256, 0, stream>>>(P2, b2, A3);

    // ---- layer 3: (4096 x 32768) x (512 x 32768)^T, split-K x8, deterministic reduce
    conv_C<2048, 512><<<dim3(2048 / 256, 512), 256, 0, stream>>>(C3, B3);
    kan_gemm<32768, 512, 8><<<dim3(16, 2, 8), 512, 0, stream>>>(A3, B3, P3);
    reduce_out<512, 8><<<dim3((BATCH * 512 / 4) / 256), 256, 0, stream>>>(P3, b3, out);
}